// Round 13
// baseline (164.359 us; speedup 1.0000x reference)
//
#include <hip/hip_runtime.h>
#include <math.h>

#define NJ 960           // tail columns (global 64..1023)
#define NSRC 896         // tail sources (global 128..1023)
#define NWARM 25

typedef unsigned long long u64;
typedef unsigned int u32;

// ws layout:
//   u64 idx: RK[896] tag|(rE|rI<<16), CT[960] tag|(cntE|cntI<<16),
//            HD[960] tag|float(hd[j])
//   float idx 8192 : Wk[64][960]  (built by front_k blocks 31..60)
//   float idx 69632: base[960]    (plain floats; K1->K2 kernel boundary orders)
#define RK_O 0u
#define CT_O 896u
#define HD_O 1856u
#define WK_F 8192u
#define BASE_F 69632u

#define TAG_RK 0x524B0001u
#define TAG_CT 0x43540001u
#define TAG_HD 0x48440001u

__device__ __forceinline__ void ast(u64* p, u64 v) {
  __hip_atomic_store(p, v, __ATOMIC_RELAXED, __HIP_MEMORY_SCOPE_AGENT);
}
__device__ __forceinline__ u64 ald(const u64* p) {
  return __hip_atomic_load(p, __ATOMIC_RELAXED, __HIP_MEMORY_SCOPE_AGENT);
}
__device__ __forceinline__ u32 poll32(const u64* p, u32 tag) {
  u64 v = ald(p);
  while ((u32)(v >> 32) != tag) { __builtin_amdgcn_s_sleep(8); v = ald(p); }
  return (u32)v;
}

// K1, grid 61 x 256 — VERBATIM round-8 front_k (62.1 us measured; R12's
// 4-barrier variant was 64.6 -> reverted). Scan floor is ~2.4 us/iter at
// this wave count (1w/4w/8w = 3.7/2.4/3.6 — bracketed optimum); likely
// clock-limited at 0.7% VALUBusy. Line closed.
__global__ __launch_bounds__(256) void front_k(const float* __restrict__ ident,
                                               const float* __restrict__ enh,
                                               const float* __restrict__ inh,
                                               const float* __restrict__ beta,
                                               const float* __restrict__ delta,
                                               void* __restrict__ wsv) {
  u64* RK = (u64*)wsv + RK_O;
  u64* CT = (u64*)wsv + CT_O;
  u64* HD = (u64*)wsv + HD_O;
  float* Wk = (float*)wsv + WK_F;
  float* base = (float*)wsv + BASE_F;

  const int tid = threadIdx.x;
  const float bb = beta[0];
  const float dN = delta[0] / 1024.0f;

  if (blockIdx.x > 30) {
    // ---------------- part D: Wk table (proven) ----------------
    const int g2 = (int)(blockIdx.x - 31) * 256 + tid;   // 0..7679
    int k = g2 / 120;
    int jb = (g2 % 120) * 8;
    float ek = enh[k], ik = inh[k];
    #pragma unroll
    for (int u = 0; u < 8; ++u) {
      float cj = ident[64 + jb + u];
      Wk[(size_t)k * NJ + jb + u] =
          dN * (expf(-bb * fabsf(ek - cj)) - expf(-bb * fabsf(ik - cj)));
    }
    return;
  }

  if (blockIdx.x > 0) {
    // ---------------- prep blocks A/B/C (proven) ----------------
    const int g = (int)(blockIdx.x - 1) * 256 + tid;   // 0..7679
    const int c8 = g & 7;
    if (g < NSRC * 8) {
      int m = g >> 3;
      float myE = enh[128 + m], myI = inh[128 + m];
      int re = 0, ri = 0;
      for (int i = 112 * c8; i < 112 * c8 + 112; ++i) {
        float ev = enh[128 + i], iv = inh[128 + i];
        re += (ev < myE || (ev == myE && i < m)) ? 1 : 0;
        ri += (iv < myI || (iv == myI && i < m)) ? 1 : 0;
      }
      int p = re | (ri << 16);
      p += __shfl_xor(p, 1); p += __shfl_xor(p, 2); p += __shfl_xor(p, 4);
      if (c8 == 0) ast(&RK[m], ((u64)TAG_RK << 32) | (u32)p);
    }
    {
      int j = g >> 3;
      float cj = ident[64 + j];
      int ce = 0, ci = 0;
      for (int i = 112 * c8; i < 112 * c8 + 112; ++i) {
        ce += (enh[128 + i] <= cj) ? 1 : 0;
        ci += (inh[128 + i] <= cj) ? 1 : 0;
      }
      int p = ce | (ci << 16);
      p += __shfl_xor(p, 1); p += __shfl_xor(p, 2); p += __shfl_xor(p, 4);
      if (c8 == 0) ast(&CT[j], ((u64)TAG_CT << 32) | (u32)p);
    }
    {
      int j = g >> 3;
      float cj = ident[64 + j];
      float h = 0.0f;
      for (int k = 8 * c8; k < 8 * c8 + 8; ++k)
        h += expf(-bb * fabsf(enh[k] - cj)) - expf(-bb * fabsf(inh[k] - cj));
      h += __shfl_xor(h, 1); h += __shfl_xor(h, 2); h += __shfl_xor(h, 4);
      if (c8 == 0)
        ast(&HD[j], ((u64)TAG_HD << 32) |
                    (u64)__float_as_uint(dN * h * (1.0f / 1024.0f)));
    }
    return;
  }

  // ---------------- block 0: 4-wave scan (R8 proven) ----------------
  __shared__ float yl[NJ];
  __shared__ float2 scanE[1024];
  __shared__ float2 scanI[1024];
  __shared__ float4 wtot[4];
  __shared__ float ssw[4];

  const int lane = tid & 63, wvid = tid >> 6;

  int rE[4], rI[4];
  if (tid < 224) {
    #pragma unroll
    for (int s = 0; s < 4; ++s) {
      u32 v = poll32(&RK[4 * tid + s], TAG_RK);
      rE[s] = v & 0xFFFF; rI[s] = v >> 16;
    }
  }
  int cE[4], cI[4];
  float hd[4], fm[4], fp[4];
  if (tid < 240) {
    #pragma unroll
    for (int c = 0; c < 4; ++c) {
      u32 v = poll32(&CT[4 * tid + c], TAG_CT);
      cE[c] = v & 0xFFFF; cI[c] = v >> 16;
      hd[c] = __uint_as_float(poll32(&HD[4 * tid + c], TAG_HD));
      float cj = ident[64 + 4 * tid + c];
      fm[c] = expf(-bb * cj); fp[c] = expf(bb * cj);
    }
  }
  float EP[4], EN[4], IP[4], IN2[4];
  if (tid < 224) {
    #pragma unroll
    for (int s = 0; s < 4; ++s) {
      float e = enh[128 + 4 * tid + s], i2 = inh[128 + 4 * tid + s];
      EP[s] = expf(bb * e);  EN[s] = expf(-bb * e);
      IP[s] = expf(bb * i2); IN2[s] = expf(-bb * i2);
    }
  }
  float y_own[4] = {1.0f / 1024.0f, 1.0f / 1024.0f, 1.0f / 1024.0f, 1.0f / 1024.0f};
  if (tid < 240) {
    #pragma unroll
    for (int c = 0; c < 4; ++c) yl[4 * tid + c] = 1.0f / 1024.0f;
  }
  __syncthreads();

  for (int t = 0; t <= NWARM; ++t) {
    if (tid == 0) {
      scanE[0] = make_float2(0.f, 0.f);
      scanI[0] = make_float2(0.f, 0.f);
    }
    if (tid >= 224) {
      #pragma unroll
      for (int c = 0; c < 4; ++c) {
        int p = 4 * tid + c;
        if (p > NSRC) {
          scanE[p] = make_float2(0.f, 0.f);
          scanI[p] = make_float2(0.f, 0.f);
        }
      }
    }
    if (tid < 224) {
      #pragma unroll
      for (int s = 0; s < 4; ++s) {
        float ym = yl[64 + 4 * tid + s];
        scanE[rE[s] + 1] = make_float2(ym * EP[s], ym * EN[s]);
        scanI[rI[s] + 1] = make_float2(ym * IP[s], ym * IN2[s]);
      }
    }
    __syncthreads();

    float2 e0 = scanE[4 * tid], e1 = scanE[4 * tid + 1],
           e2 = scanE[4 * tid + 2], e3 = scanE[4 * tid + 3];
    float2 i0 = scanI[4 * tid], i1 = scanI[4 * tid + 1],
           i2v = scanI[4 * tid + 2], i3 = scanI[4 * tid + 3];
    e1.x += e0.x; e1.y += e0.y; e2.x += e1.x; e2.y += e1.y; e3.x += e2.x; e3.y += e2.y;
    i1.x += i0.x; i1.y += i0.y; i2v.x += i1.x; i2v.y += i1.y; i3.x += i2v.x; i3.y += i2v.y;
    float4 tot = make_float4(e3.x, e3.y, i3.x, i3.y);
    float4 inc = tot;
    #pragma unroll
    for (int off = 1; off < 64; off <<= 1) {
      float ox = __shfl_up(inc.x, off, 64);
      float oy = __shfl_up(inc.y, off, 64);
      float oz = __shfl_up(inc.z, off, 64);
      float ow = __shfl_up(inc.w, off, 64);
      if (lane >= off) { inc.x += ox; inc.y += oy; inc.z += oz; inc.w += ow; }
    }
    if (lane == 63) wtot[wvid] = inc;
    __syncthreads();
    float4 exc = make_float4(inc.x - tot.x, inc.y - tot.y,
                             inc.z - tot.z, inc.w - tot.w);
    #pragma unroll
    for (int w = 0; w < 3; ++w)
      if (w < wvid) {
        float4 p = wtot[w];
        exc.x += p.x; exc.y += p.y; exc.z += p.z; exc.w += p.w;
      }
    e0.x += exc.x; e0.y += exc.y; e1.x += exc.x; e1.y += exc.y;
    e2.x += exc.x; e2.y += exc.y; e3.x += exc.x; e3.y += exc.y;
    i0.x += exc.z; i0.y += exc.w; i1.x += exc.z; i1.y += exc.w;
    i2v.x += exc.z; i2v.y += exc.w; i3.x += exc.z; i3.y += exc.w;
    scanE[4 * tid] = e0; scanE[4 * tid + 1] = e1;
    scanE[4 * tid + 2] = e2; scanE[4 * tid + 3] = e3;
    scanI[4 * tid] = i0; scanI[4 * tid + 1] = i1;
    scanI[4 * tid + 2] = i2v; scanI[4 * tid + 3] = i3;
    __syncthreads();

    float nv[4] = {0.f, 0.f, 0.f, 0.f};
    float psum = 0.0f;
    if (tid < 240) {
      float2 TE = scanE[NSRC], TI = scanI[NSRC];
      #pragma unroll
      for (int c = 0; c < 4; ++c) {
        float2 AE = scanE[cE[c]], AI = scanI[cI[c]];
        float dot = fm[c] * AE.x + fp[c] * (TE.y - AE.y)
                  - fm[c] * AI.x - fp[c] * (TI.y - AI.y);
        float pre = y_own[c] + dN * dot;
        if (t < NWARM) {
          nv[c] = fmaxf(pre + hd[c], 0.0f);
          psum += nv[c];
        } else {
          base[4 * tid + c] = pre;   // plain store; K2 reads after boundary
        }
      }
    }
    if (t < NWARM) {
      #pragma unroll
      for (int off = 32; off >= 1; off >>= 1) psum += __shfl_xor(psum, off);
      if (lane == 0) ssw[wvid] = psum;
      __syncthreads();
      float s = ssw[0] + ssw[1] + ssw[2] + ssw[3];
      float inv = (s > 0.0f) ? 1.0f / s : 1.0f;
      if (tid < 240) {
        #pragma unroll
        for (int c = 0; c < 4; ++c) {
          y_own[c] = nv[c] * inv;
          yl[4 * tid + c] = y_own[c];
        }
      }
    }
    __syncthreads();
  }
}

// K2: 8x8 micro-tile rebuild. Roofline per wave per kk-step:
//   4x8 tile (R8): 3 b128 (12 floats) / 32 FMA -> LDS ~36cyc vs FMA 16cyc
//                  => LDS-read-bound (~45 us measured-by-residual)
//   8x8 tile:      4 b128 (16 floats) / 64 FMA -> LDS 48cyc vs FMA 128cyc
//                  => FMA-bound (13.6 us/CU floor)
// 512 blocks x 256 threads (4 waves, 32 rows/block) -> 2 blocks/CU: one
// block's Wl staging hides under the other's MMA. Conflict-free
// lane-contiguous Wl reads (16B stride); At[64][36] (144B row stride,
// 16B-aligned b128 for every kk); (256,2) -> cap 128, live ~110 (R4-proven
// no-spill); output chunk (cols 0..511) last -> stores from live acc.
__global__ __launch_bounds__(256, 2) void batch_k(const float* __restrict__ inp,
                                                  const float* __restrict__ ws,
                                                  float* __restrict__ out) {
  __shared__ float At[64][36];
  __shared__ float Wl[16][512];
  __shared__ float bch[NJ];

  const int tid = threadIdx.x;
  const int colg = tid & 63;
  const int rowg = tid >> 6;                 // 4 waves, 8 rows each
  const size_t rowbase = (size_t)blockIdx.x * 32;
  const float* __restrict__ Wk = ws + WK_F;

  #pragma unroll
  for (int i = 0; i < 2; ++i) {
    int fi = tid + i * 256;                  // 0..511: 32 rows x 16 quads
    int r = fi >> 4, c4 = (fi & 15) * 4;
    float4 f4 = *(const float4*)(inp + (rowbase + r) * 64 + c4);
    At[c4 + 0][r] = f4.x; At[c4 + 1][r] = f4.y;
    At[c4 + 2][r] = f4.z; At[c4 + 3][r] = f4.w;
  }
  if (tid < 240) {
    float4 b4 = *(const float4*)(ws + BASE_F + 4 * tid);
    bch[4 * tid + 0] = b4.x; bch[4 * tid + 1] = b4.y;
    bch[4 * tid + 2] = b4.z; bch[4 * tid + 3] = b4.w;
  }

  float acc[8][8];
  float rs[8];
  #pragma unroll
  for (int r = 0; r < 8; ++r) rs[r] = 0.0f;

  #pragma unroll 1
  for (int ch = 0; ch < 2; ++ch) {
    const int c0 = ch ? 0 : 512;             // output chunk (cols 0..511) last

    #pragma unroll
    for (int r = 0; r < 8; ++r)
      #pragma unroll
      for (int c = 0; c < 8; ++c) acc[r][c] = 0.0f;

    #pragma unroll 1
    for (int s = 0; s < 4; ++s) {
      __syncthreads();
      #pragma unroll 4
      for (int i = 0; i < 8; ++i) {          // stage 16x512 Wl from Wk (L2)
        int fi = tid + i * 256;              // 0..2047
        int kk = fi >> 7;                    // 0..15
        int c4 = (fi & 127) * 4;             // 0..508
        int j = c0 + c4;
        float4 v = make_float4(0.f, 0.f, 0.f, 0.f);
        if (j < NJ)                          // j mult of 4 -> j<=956 full quad
          v = *(const float4*)(Wk + (size_t)(16 * s + kk) * NJ + j);
        *(float4*)&Wl[kk][c4] = v;
      }
      __syncthreads();
      #pragma unroll
      for (int kk = 0; kk < 16; ++kk) {
        float4 a0 = *(const float4*)&At[16 * s + kk][rowg * 8];      // bcast
        float4 a1 = *(const float4*)&At[16 * s + kk][rowg * 8 + 4];  // bcast
        float4 w0 = *(const float4*)&Wl[kk][colg * 4];        // conflict-free
        float4 w1 = *(const float4*)&Wl[kk][256 + colg * 4];  // conflict-free
        float a_[8] = {a0.x, a0.y, a0.z, a0.w, a1.x, a1.y, a1.z, a1.w};
        float w_[8] = {w0.x, w0.y, w0.z, w0.w, w1.x, w1.y, w1.z, w1.w};
        #pragma unroll
        for (int r = 0; r < 8; ++r)
          #pragma unroll
          for (int c = 0; c < 8; ++c)
            acc[r][c] = fmaf(a_[r], w_[c], acc[r][c]);
      }
    }

    // per-chunk epilogue: relu row-sum (bias known from the start)
    #pragma unroll
    for (int c = 0; c < 8; ++c) {
      int cl = (c < 4) ? (colg * 4 + c) : (256 + colg * 4 + (c - 4));
      int j = c0 + cl;
      float bv = (j < NJ) ? bch[j] : -1.0e30f;   // acc is 0 there
      #pragma unroll
      for (int r = 0; r < 8; ++r)
        rs[r] += fmaxf(acc[r][c] + bv, 0.0f);
    }
  }

  #pragma unroll
  for (int r = 0; r < 8; ++r) {
    float v = rs[r];
    #pragma unroll
    for (int off = 32; off >= 1; off >>= 1) v += __shfl_xor(v, off);
    rs[r] = v;
  }
  // acc holds chunk cols 0..511; lanes colg<16 cover out cols 0..63 via
  // cl = colg*4 + c (c=0..3) -> acc[r][0..3].
  if (colg < 16) {
    #pragma unroll
    for (int r = 0; r < 8; ++r) {
      float inv = (rs[r] > 0.0f) ? 1.0f / rs[r] : 1.0f;
      float* op = out + (rowbase + rowg * 8 + r) * 64 + colg * 4;
      float4 o;
      o.x = fmaxf(acc[r][0] + bch[colg * 4 + 0], 0.0f) * inv;
      o.y = fmaxf(acc[r][1] + bch[colg * 4 + 1], 0.0f) * inv;
      o.z = fmaxf(acc[r][2] + bch[colg * 4 + 2], 0.0f) * inv;
      o.w = fmaxf(acc[r][3] + bch[colg * 4 + 3], 0.0f) * inv;
      *(float4*)op = o;
    }
  }
}

extern "C" void kernel_launch(void* const* d_in, const int* in_sizes, int n_in,
                              void* d_out, int out_size, void* d_ws, size_t ws_size,
                              hipStream_t stream) {
  const float* inp   = (const float*)d_in[0];
  const float* ident = (const float*)d_in[1];
  const float* enh   = (const float*)d_in[2];
  const float* inh   = (const float*)d_in[3];
  const float* beta  = (const float*)d_in[4];
  const float* delta = (const float*)d_in[5];

  hipLaunchKernelGGL(front_k, dim3(61), dim3(256), 0, stream,
                     ident, enh, inh, beta, delta, d_ws);
  hipLaunchKernelGGL(batch_k, dim3(512), dim3(256), 0, stream,
                     inp, (const float*)d_ws, (float*)d_out);
}

// Round 14
// 158.998 us; speedup vs baseline: 1.0337x; 1.0337x over previous
//
#include <hip/hip_runtime.h>
#include <math.h>

#define NJ 960           // tail columns (global 64..1023)
#define NSRC 896         // tail sources (global 128..1023)
#define NWARM 25

typedef unsigned long long u64;
typedef unsigned int u32;

// ws layout:
//   u64 idx: RK[896] tag|(rE|rI<<16), CT[960] tag|(cntE|cntI<<16),
//            HD[960] tag|float(hd[j])
//   float idx 8192 : Wk[64][960]  (built by front_k blocks 31..60)
//   float idx 69632: base[960]    (plain floats; K1->K2 kernel boundary orders)
#define RK_O 0u
#define CT_O 896u
#define HD_O 1856u
#define WK_F 8192u
#define BASE_F 69632u

#define TAG_RK 0x524B0001u
#define TAG_CT 0x43540001u
#define TAG_HD 0x48440001u

__device__ __forceinline__ void ast(u64* p, u64 v) {
  __hip_atomic_store(p, v, __ATOMIC_RELAXED, __HIP_MEMORY_SCOPE_AGENT);
}
__device__ __forceinline__ u64 ald(const u64* p) {
  return __hip_atomic_load(p, __ATOMIC_RELAXED, __HIP_MEMORY_SCOPE_AGENT);
}
__device__ __forceinline__ u32 poll32(const u64* p, u32 tag) {
  u64 v = ald(p);
  while ((u32)(v >> 32) != tag) { __builtin_amdgcn_s_sleep(8); v = ald(p); }
  return (u32)v;
}

// K1, grid 61 x 256 — VERBATIM round-8 front_k (62.1-62.3 us, stable across
// R8/R13). Block 0: 4-wave scan (bracketed optimum). Blocks 1..30: prep
// A/B/C. Blocks 31..60: part D (Wk) on separate blocks so its exp loops
// stay off the scan's CU. Scan line closed (R10/R11/R12 falsifications).
__global__ __launch_bounds__(256) void front_k(const float* __restrict__ ident,
                                               const float* __restrict__ enh,
                                               const float* __restrict__ inh,
                                               const float* __restrict__ beta,
                                               const float* __restrict__ delta,
                                               void* __restrict__ wsv) {
  u64* RK = (u64*)wsv + RK_O;
  u64* CT = (u64*)wsv + CT_O;
  u64* HD = (u64*)wsv + HD_O;
  float* Wk = (float*)wsv + WK_F;
  float* base = (float*)wsv + BASE_F;

  const int tid = threadIdx.x;
  const float bb = beta[0];
  const float dN = delta[0] / 1024.0f;

  if (blockIdx.x > 30) {
    // ---------------- part D: Wk table (proven) ----------------
    const int g2 = (int)(blockIdx.x - 31) * 256 + tid;   // 0..7679
    int k = g2 / 120;
    int jb = (g2 % 120) * 8;
    float ek = enh[k], ik = inh[k];
    #pragma unroll
    for (int u = 0; u < 8; ++u) {
      float cj = ident[64 + jb + u];
      Wk[(size_t)k * NJ + jb + u] =
          dN * (expf(-bb * fabsf(ek - cj)) - expf(-bb * fabsf(ik - cj)));
    }
    return;
  }

  if (blockIdx.x > 0) {
    // ---------------- prep blocks A/B/C (proven) ----------------
    const int g = (int)(blockIdx.x - 1) * 256 + tid;   // 0..7679
    const int c8 = g & 7;
    if (g < NSRC * 8) {
      int m = g >> 3;
      float myE = enh[128 + m], myI = inh[128 + m];
      int re = 0, ri = 0;
      for (int i = 112 * c8; i < 112 * c8 + 112; ++i) {
        float ev = enh[128 + i], iv = inh[128 + i];
        re += (ev < myE || (ev == myE && i < m)) ? 1 : 0;
        ri += (iv < myI || (iv == myI && i < m)) ? 1 : 0;
      }
      int p = re | (ri << 16);
      p += __shfl_xor(p, 1); p += __shfl_xor(p, 2); p += __shfl_xor(p, 4);
      if (c8 == 0) ast(&RK[m], ((u64)TAG_RK << 32) | (u32)p);
    }
    {
      int j = g >> 3;
      float cj = ident[64 + j];
      int ce = 0, ci = 0;
      for (int i = 112 * c8; i < 112 * c8 + 112; ++i) {
        ce += (enh[128 + i] <= cj) ? 1 : 0;
        ci += (inh[128 + i] <= cj) ? 1 : 0;
      }
      int p = ce | (ci << 16);
      p += __shfl_xor(p, 1); p += __shfl_xor(p, 2); p += __shfl_xor(p, 4);
      if (c8 == 0) ast(&CT[j], ((u64)TAG_CT << 32) | (u32)p);
    }
    {
      int j = g >> 3;
      float cj = ident[64 + j];
      float h = 0.0f;
      for (int k = 8 * c8; k < 8 * c8 + 8; ++k)
        h += expf(-bb * fabsf(enh[k] - cj)) - expf(-bb * fabsf(inh[k] - cj));
      h += __shfl_xor(h, 1); h += __shfl_xor(h, 2); h += __shfl_xor(h, 4);
      if (c8 == 0)
        ast(&HD[j], ((u64)TAG_HD << 32) |
                    (u64)__float_as_uint(dN * h * (1.0f / 1024.0f)));
    }
    return;
  }

  // ---------------- block 0: 4-wave scan (R8 proven) ----------------
  __shared__ float yl[NJ];
  __shared__ float2 scanE[1024];
  __shared__ float2 scanI[1024];
  __shared__ float4 wtot[4];
  __shared__ float ssw[4];

  const int lane = tid & 63, wvid = tid >> 6;

  int rE[4], rI[4];
  if (tid < 224) {
    #pragma unroll
    for (int s = 0; s < 4; ++s) {
      u32 v = poll32(&RK[4 * tid + s], TAG_RK);
      rE[s] = v & 0xFFFF; rI[s] = v >> 16;
    }
  }
  int cE[4], cI[4];
  float hd[4], fm[4], fp[4];
  if (tid < 240) {
    #pragma unroll
    for (int c = 0; c < 4; ++c) {
      u32 v = poll32(&CT[4 * tid + c], TAG_CT);
      cE[c] = v & 0xFFFF; cI[c] = v >> 16;
      hd[c] = __uint_as_float(poll32(&HD[4 * tid + c], TAG_HD));
      float cj = ident[64 + 4 * tid + c];
      fm[c] = expf(-bb * cj); fp[c] = expf(bb * cj);
    }
  }
  float EP[4], EN[4], IP[4], IN2[4];
  if (tid < 224) {
    #pragma unroll
    for (int s = 0; s < 4; ++s) {
      float e = enh[128 + 4 * tid + s], i2 = inh[128 + 4 * tid + s];
      EP[s] = expf(bb * e);  EN[s] = expf(-bb * e);
      IP[s] = expf(bb * i2); IN2[s] = expf(-bb * i2);
    }
  }
  float y_own[4] = {1.0f / 1024.0f, 1.0f / 1024.0f, 1.0f / 1024.0f, 1.0f / 1024.0f};
  if (tid < 240) {
    #pragma unroll
    for (int c = 0; c < 4; ++c) yl[4 * tid + c] = 1.0f / 1024.0f;
  }
  __syncthreads();

  for (int t = 0; t <= NWARM; ++t) {
    if (tid == 0) {
      scanE[0] = make_float2(0.f, 0.f);
      scanI[0] = make_float2(0.f, 0.f);
    }
    if (tid >= 224) {
      #pragma unroll
      for (int c = 0; c < 4; ++c) {
        int p = 4 * tid + c;
        if (p > NSRC) {
          scanE[p] = make_float2(0.f, 0.f);
          scanI[p] = make_float2(0.f, 0.f);
        }
      }
    }
    if (tid < 224) {
      #pragma unroll
      for (int s = 0; s < 4; ++s) {
        float ym = yl[64 + 4 * tid + s];
        scanE[rE[s] + 1] = make_float2(ym * EP[s], ym * EN[s]);
        scanI[rI[s] + 1] = make_float2(ym * IP[s], ym * IN2[s]);
      }
    }
    __syncthreads();

    float2 e0 = scanE[4 * tid], e1 = scanE[4 * tid + 1],
           e2 = scanE[4 * tid + 2], e3 = scanE[4 * tid + 3];
    float2 i0 = scanI[4 * tid], i1 = scanI[4 * tid + 1],
           i2v = scanI[4 * tid + 2], i3 = scanI[4 * tid + 3];
    e1.x += e0.x; e1.y += e0.y; e2.x += e1.x; e2.y += e1.y; e3.x += e2.x; e3.y += e2.y;
    i1.x += i0.x; i1.y += i0.y; i2v.x += i1.x; i2v.y += i1.y; i3.x += i2v.x; i3.y += i2v.y;
    float4 tot = make_float4(e3.x, e3.y, i3.x, i3.y);
    float4 inc = tot;
    #pragma unroll
    for (int off = 1; off < 64; off <<= 1) {
      float ox = __shfl_up(inc.x, off, 64);
      float oy = __shfl_up(inc.y, off, 64);
      float oz = __shfl_up(inc.z, off, 64);
      float ow = __shfl_up(inc.w, off, 64);
      if (lane >= off) { inc.x += ox; inc.y += oy; inc.z += oz; inc.w += ow; }
    }
    if (lane == 63) wtot[wvid] = inc;
    __syncthreads();
    float4 exc = make_float4(inc.x - tot.x, inc.y - tot.y,
                             inc.z - tot.z, inc.w - tot.w);
    #pragma unroll
    for (int w = 0; w < 3; ++w)
      if (w < wvid) {
        float4 p = wtot[w];
        exc.x += p.x; exc.y += p.y; exc.z += p.z; exc.w += p.w;
      }
    e0.x += exc.x; e0.y += exc.y; e1.x += exc.x; e1.y += exc.y;
    e2.x += exc.x; e2.y += exc.y; e3.x += exc.x; e3.y += exc.y;
    i0.x += exc.z; i0.y += exc.w; i1.x += exc.z; i1.y += exc.w;
    i2v.x += exc.z; i2v.y += exc.w; i3.x += exc.z; i3.y += exc.w;
    scanE[4 * tid] = e0; scanE[4 * tid + 1] = e1;
    scanE[4 * tid + 2] = e2; scanE[4 * tid + 3] = e3;
    scanI[4 * tid] = i0; scanI[4 * tid + 1] = i1;
    scanI[4 * tid + 2] = i2v; scanI[4 * tid + 3] = i3;
    __syncthreads();

    float nv[4] = {0.f, 0.f, 0.f, 0.f};
    float psum = 0.0f;
    if (tid < 240) {
      float2 TE = scanE[NSRC], TI = scanI[NSRC];
      #pragma unroll
      for (int c = 0; c < 4; ++c) {
        float2 AE = scanE[cE[c]], AI = scanI[cI[c]];
        float dot = fm[c] * AE.x + fp[c] * (TE.y - AE.y)
                  - fm[c] * AI.x - fp[c] * (TI.y - AI.y);
        float pre = y_own[c] + dN * dot;
        if (t < NWARM) {
          nv[c] = fmaxf(pre + hd[c], 0.0f);
          psum += nv[c];
        } else {
          base[4 * tid + c] = pre;   // plain store; K2 reads after boundary
        }
      }
    }
    if (t < NWARM) {
      #pragma unroll
      for (int off = 32; off >= 1; off >>= 1) psum += __shfl_xor(psum, off);
      if (lane == 0) ssw[wvid] = psum;
      __syncthreads();
      float s = ssw[0] + ssw[1] + ssw[2] + ssw[3];
      float inv = (s > 0.0f) ? 1.0f / s : 1.0f;
      if (tid < 240) {
        #pragma unroll
        for (int c = 0; c < 4; ++c) {
          y_own[c] = nv[c] * inv;
          yl[4 * tid + c] = y_own[c];
        }
      }
    }
    __syncthreads();
  }
}

// K2: VERBATIM round-0 batch_t — the best batch ever measured (~31 us by
// residual: R0 bench 158.6 = front 80.8 + batch + ~47 harness). 256 blocks
// x 512 threads, 64 rows/block, 8x8 micro-tile; FMA-bound (the odd-stride
// LDS conflicts hide under FMA slack — R7's "conflict fix" diagnosis was
// wrong, and all reshapes since regressed). Output chunk processed last ->
// stores from live acc.
__global__ __launch_bounds__(512) void batch_t(const float* __restrict__ inp,
                                               const float* __restrict__ ws,
                                               float* __restrict__ out) {
  __shared__ float At[64][66];
  __shared__ float Wl[16][516];
  __shared__ float bch[512];

  const int tid = threadIdx.x;
  const int colg = tid & 63;
  const int rowg = tid >> 6;
  const size_t rowbase = (size_t)blockIdx.x * 64;
  const float* __restrict__ Wk = ws + WK_F;
  const float* __restrict__ base = ws + BASE_F;

  #pragma unroll
  for (int i = 0; i < 2; ++i) {
    int fi = tid + i * 512;
    int r = fi >> 4, c4 = (fi & 15) * 4;
    float4 f4 = *(const float4*)(inp + (rowbase + r) * 64 + c4);
    At[c4 + 0][r] = f4.x; At[c4 + 1][r] = f4.y;
    At[c4 + 2][r] = f4.z; At[c4 + 3][r] = f4.w;
  }

  float rs[8];
  #pragma unroll
  for (int r = 0; r < 8; ++r) rs[r] = 0.0f;
  float acc[8][8];

  #pragma unroll 1
  for (int ch = 0; ch < 2; ++ch) {
    const int c0 = ch ? 0 : 512;
    #pragma unroll
    for (int r = 0; r < 8; ++r)
      #pragma unroll
      for (int c = 0; c < 8; ++c) acc[r][c] = 0.0f;

    __syncthreads();
    {
      int j = c0 + tid;
      bch[tid] = (j < 960) ? base[j] : -1.0e30f;
    }

    #pragma unroll 1
    for (int s = 0; s < 4; ++s) {
      __syncthreads();
      #pragma unroll
      for (int i = 0; i < 4; ++i) {
        int fi = tid + i * 512;
        int kk = fi >> 7;
        int c4 = (fi & 127) * 4;
        int j = c0 + c4;
        float4 v = make_float4(0.f, 0.f, 0.f, 0.f);
        if (j < 960)
          v = *(const float4*)(Wk + (size_t)(16 * s + kk) * NJ + j);
        *(float4*)&Wl[kk][c4] = v;
      }
      __syncthreads();

      #pragma unroll
      for (int kk = 0; kk < 16; ++kk) {
        float4 a0 = *(const float4*)&At[16 * s + kk][rowg * 8];
        float4 a1 = *(const float4*)&At[16 * s + kk][rowg * 8 + 4];
        float4 w0 = *(const float4*)&Wl[kk][colg * 8];
        float4 w1 = *(const float4*)&Wl[kk][colg * 8 + 4];
        float a[8] = {a0.x, a0.y, a0.z, a0.w, a1.x, a1.y, a1.z, a1.w};
        float w[8] = {w0.x, w0.y, w0.z, w0.w, w1.x, w1.y, w1.z, w1.w};
        #pragma unroll
        for (int r = 0; r < 8; ++r)
          #pragma unroll
          for (int c = 0; c < 8; ++c)
            acc[r][c] = fmaf(a[r], w[c], acc[r][c]);
      }
    }

    #pragma unroll
    for (int c = 0; c < 8; ++c) {
      float bv = bch[colg * 8 + c];
      #pragma unroll
      for (int r = 0; r < 8; ++r)
        rs[r] += fmaxf(acc[r][c] + bv, 0.0f);
    }
  }

  #pragma unroll
  for (int r = 0; r < 8; ++r) {
    float v = rs[r];
    #pragma unroll
    for (int off = 32; off >= 1; off >>= 1) v += __shfl_xor(v, off);
    rs[r] = v;
  }

  if (colg < 8) {
    #pragma unroll
    for (int r = 0; r < 8; ++r) {
      float inv = (rs[r] > 0.0f) ? 1.0f / rs[r] : 1.0f;
      float* op = out + (rowbase + rowg * 8 + r) * 64 + colg * 8;
      float4 o;
      o.x = fmaxf(acc[r][0] + bch[colg * 8 + 0], 0.0f) * inv;
      o.y = fmaxf(acc[r][1] + bch[colg * 8 + 1], 0.0f) * inv;
      o.z = fmaxf(acc[r][2] + bch[colg * 8 + 2], 0.0f) * inv;
      o.w = fmaxf(acc[r][3] + bch[colg * 8 + 3], 0.0f) * inv;
      *(float4*)op = o;
      o.x = fmaxf(acc[r][4] + bch[colg * 8 + 4], 0.0f) * inv;
      o.y = fmaxf(acc[r][5] + bch[colg * 8 + 5], 0.0f) * inv;
      o.z = fmaxf(acc[r][6] + bch[colg * 8 + 6], 0.0f) * inv;
      o.w = fmaxf(acc[r][7] + bch[colg * 8 + 7], 0.0f) * inv;
      *(float4*)(op + 4) = o;
    }
  }
}

extern "C" void kernel_launch(void* const* d_in, const int* in_sizes, int n_in,
                              void* d_out, int out_size, void* d_ws, size_t ws_size,
                              hipStream_t stream) {
  const float* inp   = (const float*)d_in[0];
  const float* ident = (const float*)d_in[1];
  const float* enh   = (const float*)d_in[2];
  const float* inh   = (const float*)d_in[3];
  const float* beta  = (const float*)d_in[4];
  const float* delta = (const float*)d_in[5];

  hipLaunchKernelGGL(front_k, dim3(61), dim3(256), 0, stream,
                     ident, enh, inh, beta, delta, d_ws);
  hipLaunchKernelGGL(batch_t, dim3(256), dim3(512), 0, stream,
                     inp, (const float*)d_ws, (float*)d_out);
}

// Round 16
// 154.962 us; speedup vs baseline: 1.0606x; 1.0260x over previous
//
#include <hip/hip_runtime.h>
#include <math.h>

#define NJ 960           // tail columns (global 64..1023)
#define NSRC 896         // tail sources (global 128..1023)
#define NWARM 25

typedef unsigned long long u64;
typedef unsigned int u32;

// ws layout:
//   u64 idx: RK[896] tag|(rE|rI<<16), CT[960] tag|(cntE|cntI<<16),
//            HD[960] tag|float(hd[j])
//   float idx 8192 : Wk[64][960]  (built by front_k blocks 31..60)
//   float idx 69632: base[960]    (plain floats; K1->K2 kernel boundary orders)
#define RK_O 0u
#define CT_O 896u
#define HD_O 1856u
#define WK_F 8192u
#define BASE_F 69632u

#define TAG_RK 0x524B0001u
#define TAG_CT 0x43540001u
#define TAG_HD 0x48440001u

__device__ __forceinline__ void ast(u64* p, u64 v) {
  __hip_atomic_store(p, v, __ATOMIC_RELAXED, __HIP_MEMORY_SCOPE_AGENT);
}
__device__ __forceinline__ u64 ald(const u64* p) {
  return __hip_atomic_load(p, __ATOMIC_RELAXED, __HIP_MEMORY_SCOPE_AGENT);
}
__device__ __forceinline__ u32 poll32(const u64* p, u32 tag) {
  u64 v = ald(p);
  while ((u32)(v >> 32) != tag) { __builtin_amdgcn_s_sleep(8); v = ald(p); }
  return (u32)v;
}

// K1, grid 61 x 256 — best-measured configuration (R8, bench 155.054):
//   block 0      : 4-wave scan (bracketed optimum over 1/4/8 waves)
//   blocks 1..30 : prep A/B/C (ranks/counts/hd), tag-published
//   blocks 31..60: part D (Wk table) on separate blocks (keeps heavy exp
//                  loops off the scan's CU — the 80.8 -> 62.1 us lesson)
__global__ __launch_bounds__(256) void front_k(const float* __restrict__ ident,
                                               const float* __restrict__ enh,
                                               const float* __restrict__ inh,
                                               const float* __restrict__ beta,
                                               const float* __restrict__ delta,
                                               void* __restrict__ wsv) {
  u64* RK = (u64*)wsv + RK_O;
  u64* CT = (u64*)wsv + CT_O;
  u64* HD = (u64*)wsv + HD_O;
  float* Wk = (float*)wsv + WK_F;
  float* base = (float*)wsv + BASE_F;

  const int tid = threadIdx.x;
  const float bb = beta[0];
  const float dN = delta[0] / 1024.0f;

  if (blockIdx.x > 30) {
    // ---------------- part D: Wk table ----------------
    const int g2 = (int)(blockIdx.x - 31) * 256 + tid;   // 0..7679
    int k = g2 / 120;
    int jb = (g2 % 120) * 8;
    float ek = enh[k], ik = inh[k];
    #pragma unroll
    for (int u = 0; u < 8; ++u) {
      float cj = ident[64 + jb + u];
      Wk[(size_t)k * NJ + jb + u] =
          dN * (expf(-bb * fabsf(ek - cj)) - expf(-bb * fabsf(ik - cj)));
    }
    return;
  }

  if (blockIdx.x > 0) {
    // ---------------- prep blocks A/B/C ----------------
    const int g = (int)(blockIdx.x - 1) * 256 + tid;   // 0..7679
    const int c8 = g & 7;
    if (g < NSRC * 8) {
      int m = g >> 3;
      float myE = enh[128 + m], myI = inh[128 + m];
      int re = 0, ri = 0;
      for (int i = 112 * c8; i < 112 * c8 + 112; ++i) {
        float ev = enh[128 + i], iv = inh[128 + i];
        re += (ev < myE || (ev == myE && i < m)) ? 1 : 0;
        ri += (iv < myI || (iv == myI && i < m)) ? 1 : 0;
      }
      int p = re | (ri << 16);
      p += __shfl_xor(p, 1); p += __shfl_xor(p, 2); p += __shfl_xor(p, 4);
      if (c8 == 0) ast(&RK[m], ((u64)TAG_RK << 32) | (u32)p);
    }
    {
      int j = g >> 3;
      float cj = ident[64 + j];
      int ce = 0, ci = 0;
      for (int i = 112 * c8; i < 112 * c8 + 112; ++i) {
        ce += (enh[128 + i] <= cj) ? 1 : 0;
        ci += (inh[128 + i] <= cj) ? 1 : 0;
      }
      int p = ce | (ci << 16);
      p += __shfl_xor(p, 1); p += __shfl_xor(p, 2); p += __shfl_xor(p, 4);
      if (c8 == 0) ast(&CT[j], ((u64)TAG_CT << 32) | (u32)p);
    }
    {
      int j = g >> 3;
      float cj = ident[64 + j];
      float h = 0.0f;
      for (int k = 8 * c8; k < 8 * c8 + 8; ++k)
        h += expf(-bb * fabsf(enh[k] - cj)) - expf(-bb * fabsf(inh[k] - cj));
      h += __shfl_xor(h, 1); h += __shfl_xor(h, 2); h += __shfl_xor(h, 4);
      if (c8 == 0)
        ast(&HD[j], ((u64)TAG_HD << 32) |
                    (u64)__float_as_uint(dN * h * (1.0f / 1024.0f)));
    }
    return;
  }

  // ---------------- block 0: 4-wave scan ----------------
  __shared__ float yl[NJ];
  __shared__ float2 scanE[1024];
  __shared__ float2 scanI[1024];
  __shared__ float4 wtot[4];
  __shared__ float ssw[4];

  const int lane = tid & 63, wvid = tid >> 6;

  int rE[4], rI[4];
  if (tid < 224) {
    #pragma unroll
    for (int s = 0; s < 4; ++s) {
      u32 v = poll32(&RK[4 * tid + s], TAG_RK);
      rE[s] = v & 0xFFFF; rI[s] = v >> 16;
    }
  }
  int cE[4], cI[4];
  float hd[4], fm[4], fp[4];
  if (tid < 240) {
    #pragma unroll
    for (int c = 0; c < 4; ++c) {
      u32 v = poll32(&CT[4 * tid + c], TAG_CT);
      cE[c] = v & 0xFFFF; cI[c] = v >> 16;
      hd[c] = __uint_as_float(poll32(&HD[4 * tid + c], TAG_HD));
      float cj = ident[64 + 4 * tid + c];
      fm[c] = expf(-bb * cj); fp[c] = expf(bb * cj);
    }
  }
  float EP[4], EN[4], IP[4], IN2[4];
  if (tid < 224) {
    #pragma unroll
    for (int s = 0; s < 4; ++s) {
      float e = enh[128 + 4 * tid + s], i2 = inh[128 + 4 * tid + s];
      EP[s] = expf(bb * e);  EN[s] = expf(-bb * e);
      IP[s] = expf(bb * i2); IN2[s] = expf(-bb * i2);
    }
  }
  float y_own[4] = {1.0f / 1024.0f, 1.0f / 1024.0f, 1.0f / 1024.0f, 1.0f / 1024.0f};
  if (tid < 240) {
    #pragma unroll
    for (int c = 0; c < 4; ++c) yl[4 * tid + c] = 1.0f / 1024.0f;
  }
  __syncthreads();

  for (int t = 0; t <= NWARM; ++t) {
    if (tid == 0) {
      scanE[0] = make_float2(0.f, 0.f);
      scanI[0] = make_float2(0.f, 0.f);
    }
    if (tid >= 224) {
      #pragma unroll
      for (int c = 0; c < 4; ++c) {
        int p = 4 * tid + c;
        if (p > NSRC) {
          scanE[p] = make_float2(0.f, 0.f);
          scanI[p] = make_float2(0.f, 0.f);
        }
      }
    }
    if (tid < 224) {
      #pragma unroll
      for (int s = 0; s < 4; ++s) {
        float ym = yl[64 + 4 * tid + s];
        scanE[rE[s] + 1] = make_float2(ym * EP[s], ym * EN[s]);
        scanI[rI[s] + 1] = make_float2(ym * IP[s], ym * IN2[s]);
      }
    }
    __syncthreads();

    float2 e0 = scanE[4 * tid], e1 = scanE[4 * tid + 1],
           e2 = scanE[4 * tid + 2], e3 = scanE[4 * tid + 3];
    float2 i0 = scanI[4 * tid], i1 = scanI[4 * tid + 1],
           i2v = scanI[4 * tid + 2], i3 = scanI[4 * tid + 3];
    e1.x += e0.x; e1.y += e0.y; e2.x += e1.x; e2.y += e1.y; e3.x += e2.x; e3.y += e2.y;
    i1.x += i0.x; i1.y += i0.y; i2v.x += i1.x; i2v.y += i1.y; i3.x += i2v.x; i3.y += i2v.y;
    float4 tot = make_float4(e3.x, e3.y, i3.x, i3.y);
    float4 inc = tot;
    #pragma unroll
    for (int off = 1; off < 64; off <<= 1) {
      float ox = __shfl_up(inc.x, off, 64);
      float oy = __shfl_up(inc.y, off, 64);
      float oz = __shfl_up(inc.z, off, 64);
      float ow = __shfl_up(inc.w, off, 64);
      if (lane >= off) { inc.x += ox; inc.y += oy; inc.z += oz; inc.w += ow; }
    }
    if (lane == 63) wtot[wvid] = inc;
    __syncthreads();
    float4 exc = make_float4(inc.x - tot.x, inc.y - tot.y,
                             inc.z - tot.z, inc.w - tot.w);
    #pragma unroll
    for (int w = 0; w < 3; ++w)
      if (w < wvid) {
        float4 p = wtot[w];
        exc.x += p.x; exc.y += p.y; exc.z += p.z; exc.w += p.w;
      }
    e0.x += exc.x; e0.y += exc.y; e1.x += exc.x; e1.y += exc.y;
    e2.x += exc.x; e2.y += exc.y; e3.x += exc.x; e3.y += exc.y;
    i0.x += exc.z; i0.y += exc.w; i1.x += exc.z; i1.y += exc.w;
    i2v.x += exc.z; i2v.y += exc.w; i3.x += exc.z; i3.y += exc.w;
    scanE[4 * tid] = e0; scanE[4 * tid + 1] = e1;
    scanE[4 * tid + 2] = e2; scanE[4 * tid + 3] = e3;
    scanI[4 * tid] = i0; scanI[4 * tid + 1] = i1;
    scanI[4 * tid + 2] = i2v; scanI[4 * tid + 3] = i3;
    __syncthreads();

    float nv[4] = {0.f, 0.f, 0.f, 0.f};
    float psum = 0.0f;
    if (tid < 240) {
      float2 TE = scanE[NSRC], TI = scanI[NSRC];
      #pragma unroll
      for (int c = 0; c < 4; ++c) {
        float2 AE = scanE[cE[c]], AI = scanI[cI[c]];
        float dot = fm[c] * AE.x + fp[c] * (TE.y - AE.y)
                  - fm[c] * AI.x - fp[c] * (TI.y - AI.y);
        float pre = y_own[c] + dN * dot;
        if (t < NWARM) {
          nv[c] = fmaxf(pre + hd[c], 0.0f);
          psum += nv[c];
        } else {
          base[4 * tid + c] = pre;   // plain store; K2 reads after boundary
        }
      }
    }
    if (t < NWARM) {
      #pragma unroll
      for (int off = 32; off >= 1; off >>= 1) psum += __shfl_xor(psum, off);
      if (lane == 0) ssw[wvid] = psum;
      __syncthreads();
      float s = ssw[0] + ssw[1] + ssw[2] + ssw[3];
      float inv = (s > 0.0f) ? 1.0f / s : 1.0f;
      if (tid < 240) {
        #pragma unroll
        for (int c = 0; c < 4; ++c) {
          y_own[c] = nv[c] * inv;
          yl[4 * tid + c] = y_own[c];
        }
      }
    }
    __syncthreads();
  }
}

// K2: R8 batch_k — best composed batch (~43 us by residual). 512 blocks x
// 512 threads, 32 rows/block -> all 256 CUs at 2 blocks/CU. Weights
// streamed from the precomputed Wk table (L2-resident, built free under
// the scan); lane-contiguous conflict-free Wl reads; At[64][36] aligned
// b128; output chunk (cols 0..511) processed last -> stores from live acc.
__global__ __launch_bounds__(512) void batch_k(const float* __restrict__ inp,
                                               const float* __restrict__ ws,
                                               float* __restrict__ out) {
  __shared__ float At[64][36];
  __shared__ float Wl[16][512];
  __shared__ float bch[NJ];

  const int tid = threadIdx.x;
  const int colg = tid & 63;
  const int rowg = tid >> 6;                 // 8 waves, 4 rows each
  const size_t rowbase = (size_t)blockIdx.x * 32;
  const float* __restrict__ Wk = ws + WK_F;

  {
    int r = tid >> 4, c4 = (tid & 15) * 4;   // 32 rows x 16 quads
    float4 f4 = *(const float4*)(inp + (rowbase + r) * 64 + c4);
    At[c4 + 0][r] = f4.x; At[c4 + 1][r] = f4.y;
    At[c4 + 2][r] = f4.z; At[c4 + 3][r] = f4.w;
  }
  if (tid < 240) {
    float4 b4 = *(const float4*)(ws + BASE_F + 4 * tid);
    bch[4 * tid + 0] = b4.x; bch[4 * tid + 1] = b4.y;
    bch[4 * tid + 2] = b4.z; bch[4 * tid + 3] = b4.w;
  }

  float acc[4][8];
  float rs[4] = {0.f, 0.f, 0.f, 0.f};

  #pragma unroll 1
  for (int ch = 0; ch < 2; ++ch) {
    const int c0 = ch ? 0 : 512;             // output chunk (cols 0..511) last

    #pragma unroll
    for (int r = 0; r < 4; ++r)
      #pragma unroll
      for (int c = 0; c < 8; ++c) acc[r][c] = 0.0f;

    #pragma unroll 1
    for (int s = 0; s < 4; ++s) {
      __syncthreads();
      #pragma unroll
      for (int i = 0; i < 4; ++i) {          // stage 16x512 Wl from Wk (L2)
        int fi = tid + i * 512;              // 0..2047
        int kk = fi >> 7;                    // 0..15
        int c4 = (fi & 127) * 4;             // 0..508
        int j = c0 + c4;
        float4 v = make_float4(0.f, 0.f, 0.f, 0.f);
        if (j < NJ)                          // j mult of 4 -> j<=956 full quad
          v = *(const float4*)(Wk + (size_t)(16 * s + kk) * NJ + j);
        *(float4*)&Wl[kk][c4] = v;
      }
      __syncthreads();
      #pragma unroll
      for (int kk = 0; kk < 16; ++kk) {
        float4 av = *(const float4*)&At[16 * s + kk][rowg * 4];  // bcast
        float4 w0 = *(const float4*)&Wl[kk][colg * 4];        // conflict-free
        float4 w1 = *(const float4*)&Wl[kk][256 + colg * 4];  // conflict-free
        float a_[4] = {av.x, av.y, av.z, av.w};
        float w_[8] = {w0.x, w0.y, w0.z, w0.w, w1.x, w1.y, w1.z, w1.w};
        #pragma unroll
        for (int r = 0; r < 4; ++r)
          #pragma unroll
          for (int c = 0; c < 8; ++c)
            acc[r][c] = fmaf(a_[r], w_[c], acc[r][c]);
      }
    }

    // per-chunk epilogue: relu row-sum (bias known from the start)
    #pragma unroll
    for (int c = 0; c < 8; ++c) {
      int cl = (c < 4) ? (colg * 4 + c) : (256 + colg * 4 + (c - 4));
      int j = c0 + cl;
      float bv = (j < NJ) ? bch[j] : -1.0e30f;   // acc is 0 there
      #pragma unroll
      for (int r = 0; r < 4; ++r)
        rs[r] += fmaxf(acc[r][c] + bv, 0.0f);
    }
  }

  #pragma unroll
  for (int r = 0; r < 4; ++r) {
    float v = rs[r];
    #pragma unroll
    for (int off = 32; off >= 1; off >>= 1) v += __shfl_xor(v, off);
    rs[r] = v;
  }
  if (colg < 16) {
    #pragma unroll
    for (int r = 0; r < 4; ++r) {
      float inv = (rs[r] > 0.0f) ? 1.0f / rs[r] : 1.0f;
      float* op = out + (rowbase + rowg * 4 + r) * 64 + colg * 4;
      float4 o;
      o.x = fmaxf(acc[r][0] + bch[colg * 4 + 0], 0.0f) * inv;
      o.y = fmaxf(acc[r][1] + bch[colg * 4 + 1], 0.0f) * inv;
      o.z = fmaxf(acc[r][2] + bch[colg * 4 + 2], 0.0f) * inv;
      o.w = fmaxf(acc[r][3] + bch[colg * 4 + 3], 0.0f) * inv;
      *(float4*)op = o;
    }
  }
}

extern "C" void kernel_launch(void* const* d_in, const int* in_sizes, int n_in,
                              void* d_out, int out_size, void* d_ws, size_t ws_size,
                              hipStream_t stream) {
  const float* inp   = (const float*)d_in[0];
  const float* ident = (const float*)d_in[1];
  const float* enh   = (const float*)d_in[2];
  const float* inh   = (const float*)d_in[3];
  const float* beta  = (const float*)d_in[4];
  const float* delta = (const float*)d_in[5];

  hipLaunchKernelGGL(front_k, dim3(61), dim3(256), 0, stream,
                     ident, enh, inh, beta, delta, d_ws);
  hipLaunchKernelGGL(batch_k, dim3(512), dim3(512), 0, stream,
                     inp, (const float*)d_ws, (float*)d_out);
}